// Round 1
// baseline (307.755 us; speedup 1.0000x reference)
//
#include <hip/hip_runtime.h>
#include <math.h>

#define NB   2
#define H0   64
#define W0   64
#define NC   256
#define NPTS 4096
#define NLVL 4
#define NK   49   // (2*3+1)^2

__device__ __forceinline__ float wave_reduce_sum(float v) {
    for (int m = 32; m >= 1; m >>= 1)
        v += __shfl_xor(v, m, 64);
    return v;
}

// One wave per query point: bilinear sample fmap1 at coords1, L2-normalize over C.
__global__ __launch_bounds__(256)
void feat1_kernel(const float* __restrict__ fmap1,
                  const float* __restrict__ coords1,
                  float* __restrict__ feat1) {
    int pt   = blockIdx.x * 4 + (threadIdx.x >> 6);   // 0..B*N-1
    int lane = threadIdx.x & 63;
    int b = pt / NPTS;
    float x = coords1[pt * 2 + 0];
    float y = coords1[pt * 2 + 1];
    int x0 = min(max((int)floorf(x), 0), W0 - 1);
    int y0 = min(max((int)floorf(y), 0), H0 - 1);
    int x1 = min(x0 + 1, W0 - 1);
    int y1 = min(y0 + 1, H0 - 1);
    // clip-first weight semantics (zero weight at exact upper edge)
    float wxh = x - (float)x0, wxl = (float)x1 - x;
    float wyh = y - (float)y0, wyl = (float)y1 - y;
    float wa = wxl * wyl, wb = wxl * wyh, wc = wxh * wyl, wd = wxh * wyh;
    const float4* base = (const float4*)(fmap1 + (size_t)b * H0 * W0 * NC);
    float4 Ia = base[(y0 * W0 + x0) * (NC / 4) + lane];
    float4 Ib = base[(y1 * W0 + x0) * (NC / 4) + lane];
    float4 Ic = base[(y0 * W0 + x1) * (NC / 4) + lane];
    float4 Id = base[(y1 * W0 + x1) * (NC / 4) + lane];
    float vx = wa * Ia.x + wb * Ib.x + wc * Ic.x + wd * Id.x;
    float vy = wa * Ia.y + wb * Ib.y + wc * Ic.y + wd * Id.y;
    float vz = wa * Ia.z + wb * Ib.z + wc * Ic.z + wd * Id.z;
    float vw = wa * Ia.w + wb * Ib.w + wc * Ic.w + wd * Id.w;
    float ss = wave_reduce_sum(vx * vx + vy * vy + vz * vz + vw * vw);
    float inv = 1.0f / (sqrtf(ss) + 1e-6f);
    float4 o; o.x = vx * inv; o.y = vy * inv; o.z = vz * inv; o.w = vw * inv;
    ((float4*)(feat1 + (size_t)pt * NC))[lane] = o;
}

// One wave per pixel: L2-normalize over C.
__global__ __launch_bounds__(256)
void norm_kernel(const float* __restrict__ in, float* __restrict__ out, int npix) {
    int p = blockIdx.x * 4 + (threadIdx.x >> 6);
    if (p >= npix) return;
    int lane = threadIdx.x & 63;
    float4 v = ((const float4*)in)[(size_t)p * (NC / 4) + lane];
    float ss = wave_reduce_sum(v.x * v.x + v.y * v.y + v.z * v.z + v.w * v.w);
    float inv = 1.0f / (sqrtf(ss) + 1e-6f);
    float4 o; o.x = v.x * inv; o.y = v.y * inv; o.z = v.z * inv; o.w = v.w * inv;
    ((float4*)out)[(size_t)p * (NC / 4) + lane] = o;
}

// jax.image.resize bilinear antialias 2x downsample: separable [1,3,3,1]/8,
// OOB taps dropped + renormalized at edges. One wave per OUTPUT pixel.
// Writes both raw (for cascade) and normalized output.
__global__ __launch_bounds__(256)
void down_kernel(const float* __restrict__ in, float* __restrict__ raw_out,
                 float* __restrict__ norm_out, int Hi, int Wi) {
    int Ho = Hi >> 1, Wo = Wi >> 1;
    int wid = blockIdx.x * 4 + (threadIdx.x >> 6);
    int total = NB * Ho * Wo;
    if (wid >= total) return;
    int lane = threadIdx.x & 63;
    int b = wid / (Ho * Wo);
    int rem = wid - b * Ho * Wo;
    int yo = rem / Wo, xo = rem - yo * Wo;
    float wy[4], wx[4]; int ty[4], tx[4];
    float sy = 0.f, sx = 0.f;
    for (int j = 0; j < 4; ++j) {
        float w = (j == 0 || j == 3) ? 1.f : 3.f;
        int yi = 2 * yo - 1 + j;
        float wyj = (yi >= 0 && yi < Hi) ? w : 0.f;
        ty[j] = min(max(yi, 0), Hi - 1); wy[j] = wyj; sy += wyj;
        int xi = 2 * xo - 1 + j;
        float wxj = (xi >= 0 && xi < Wi) ? w : 0.f;
        tx[j] = min(max(xi, 0), Wi - 1); wx[j] = wxj; sx += wxj;
    }
    float inv_s = 1.f / (sy * sx);
    float ax = 0.f, ay = 0.f, az = 0.f, aw = 0.f;
    const float4* basep = (const float4*)(in + (size_t)b * Hi * Wi * NC);
    for (int jy = 0; jy < 4; ++jy) {
        if (wy[jy] == 0.f) continue;
        for (int jx = 0; jx < 4; ++jx) {
            float w = wy[jy] * wx[jx];
            if (w == 0.f) continue;
            float4 v = basep[(ty[jy] * Wi + tx[jx]) * (NC / 4) + lane];
            ax += w * v.x; ay += w * v.y; az += w * v.z; aw += w * v.w;
        }
    }
    ax *= inv_s; ay *= inv_s; az *= inv_s; aw *= inv_s;
    float ss = wave_reduce_sum(ax * ax + ay * ay + az * az + aw * aw);
    float inv = 1.f / (sqrtf(ss) + 1e-6f);
    size_t po = ((size_t)b * Ho * Wo + (size_t)yo * Wo + xo) * (NC / 4) + lane;
    float4 r;  r.x = ax;        r.y = ay;        r.z = az;        r.w = aw;
    float4 nn; nn.x = ax * inv; nn.y = ay * inv; nn.z = az * inv; nn.w = aw * inv;
    ((float4*)raw_out)[po]  = r;
    ((float4*)norm_out)[po] = nn;
}

// One block per point. Wave w = level. Lane = one of 8x8 grid pixels around
// floor(coords2/scale): full 256-ch dot with feat1 (LDS broadcast). Then 49
// lanes blend 4 dots with reference clip-first bilinear weights.
__global__ __launch_bounds__(256)
void corr_kernel(const float* __restrict__ feat1,
                 const float* __restrict__ coords2,
                 const float* __restrict__ f2n0, const float* __restrict__ f2n1,
                 const float* __restrict__ f2n2, const float* __restrict__ f2n3,
                 float* __restrict__ out) {
    __shared__ float f1s[NC];
    __shared__ float Ds[NLVL][64];
    int pt = blockIdx.x;
    int b  = pt / NPTS;
    int t  = threadIdx.x;
    f1s[t] = feat1[(size_t)pt * NC + t];
    __syncthreads();

    int w    = t >> 6;        // level
    int lane = t & 63;
    int Wl = W0 >> w, Hl = H0 >> w;
    float invs = 1.0f / (float)(1 << w);
    float cx = coords2[pt * 2 + 0] * invs;
    float cy = coords2[pt * 2 + 1] * invs;
    int ix = (int)floorf(cx), iy = (int)floorf(cy);

    const float* f2 = (w == 0) ? f2n0 : (w == 1) ? f2n1 : (w == 2) ? f2n2 : f2n3;
    int jx = lane & 7, jy = lane >> 3;
    int px = min(max(ix - 3 + jx, 0), Wl - 1);
    int py = min(max(iy - 3 + jy, 0), Hl - 1);
    const float4* pix = (const float4*)(f2 + (((size_t)b * Hl + py) * Wl + px) * NC);
    const float4* f1v = (const float4*)f1s;
    float acc = 0.f;
#pragma unroll 8
    for (int c = 0; c < NC / 4; ++c) {
        float4 a = f1v[c];     // lane-uniform LDS broadcast
        float4 v = pix[c];
        acc += a.x * v.x + a.y * v.y + a.z * v.z + a.w * v.w;
    }
    Ds[w][lane] = acc;
    __syncthreads();

    if (lane < NK) {
        int tyk = lane / 7, txk = lane % 7;
        float dx = (float)(txk - 3), dy = (float)(tyk - 3);
        float x = fminf(fmaxf(cx + dx, 0.f), (float)(Wl - 1));
        float y = fminf(fmaxf(cy + dy, 0.f), (float)(Hl - 1));
        int x0 = (int)floorf(x);
        int y0 = (int)floorf(y);
        int x1 = min(x0 + 1, Wl - 1);
        int y1 = min(y0 + 1, Hl - 1);
        float wxh = x - (float)x0, wxl = (float)x1 - x;  // both 0 at exact upper edge
        float wyh = y - (float)y0, wyl = (float)y1 - y;
        int sx0 = min(max(x0 - ix + 3, 0), 7);
        int sx1 = min(max(x1 - ix + 3, 0), 7);
        int sy0 = min(max(y0 - iy + 3, 0), 7);
        int sy1 = min(max(y1 - iy + 3, 0), 7);
        float v = wxl * wyl * Ds[w][sy0 * 8 + sx0]
                + wxl * wyh * Ds[w][sy1 * 8 + sx0]
                + wxh * wyl * Ds[w][sy0 * 8 + sx1]
                + wxh * wyh * Ds[w][sy1 * 8 + sx1];
        out[(size_t)pt * (NLVL * NK) + w * NK + lane] = v;
    }
}

extern "C" void kernel_launch(void* const* d_in, const int* in_sizes, int n_in,
                              void* d_out, int out_size, void* d_ws, size_t ws_size,
                              hipStream_t stream) {
    const float* fmap1   = (const float*)d_in[0];
    const float* fmap2   = (const float*)d_in[1];
    const float* coords1 = (const float*)d_in[2];
    const float* coords2 = (const float*)d_in[3];
    float* out = (float*)d_out;
    float* ws  = (float*)d_ws;

    // workspace layout (floats)
    float* feat1 = ws;                       // 2*4096*256      = 2097152
    float* f2n0  = ws + 2097152;             // 2*64*64*256     = 2097152
    float* raw1  = ws + 4194304;             // 2*32*32*256     = 524288
    float* f2n1  = ws + 4718592;             // 524288
    float* raw2  = ws + 5242880;             // 2*16*16*256     = 131072
    float* f2n2  = ws + 5373952;             // 131072
    float* raw3  = ws + 5505024;             // 2*8*8*256       = 32768
    float* f2n3  = ws + 5537792;             // 32768
    // total = 5570560 floats = 21.25 MiB

    // feat1 = normalize(bilinear(fmap1, coords1))
    feat1_kernel<<<(NB * NPTS) / 4, 256, 0, stream>>>(fmap1, coords1, feat1);
    // level 0 normalize
    norm_kernel<<<(NB * H0 * W0 + 3) / 4, 256, 0, stream>>>(fmap2, f2n0, NB * H0 * W0);
    // cascaded pyramid with fused normalize
    down_kernel<<<(NB * 32 * 32 + 3) / 4, 256, 0, stream>>>(fmap2, raw1, f2n1, 64, 64);
    down_kernel<<<(NB * 16 * 16 + 3) / 4, 256, 0, stream>>>(raw1, raw2, f2n2, 32, 32);
    down_kernel<<<(NB * 8 * 8 + 3) / 4, 256, 0, stream>>>(raw2, raw3, f2n3, 16, 16);
    // correlation
    corr_kernel<<<NB * NPTS, 256, 0, stream>>>(feat1, coords2, f2n0, f2n1, f2n2, f2n3, out);
}

// Round 2
// 228.252 us; speedup vs baseline: 1.3483x; 1.3483x over previous
//
#include <hip/hip_runtime.h>
#include <math.h>

#define NB   2
#define H0   64
#define W0   64
#define NC   256
#define NPTS 4096
#define NLVL 4
#define NK   49   // (2*3+1)^2

__device__ __forceinline__ float wave_reduce_sum(float v) {
    for (int m = 32; m >= 1; m >>= 1)
        v += __shfl_xor(v, m, 64);
    return v;
}

// One wave per query point: bilinear sample fmap1 at coords1, L2-normalize over C.
__global__ __launch_bounds__(256)
void feat1_kernel(const float* __restrict__ fmap1,
                  const float* __restrict__ coords1,
                  float* __restrict__ feat1) {
    int pt   = blockIdx.x * 4 + (threadIdx.x >> 6);   // 0..B*N-1
    int lane = threadIdx.x & 63;
    int b = pt / NPTS;
    float x = coords1[pt * 2 + 0];
    float y = coords1[pt * 2 + 1];
    int x0 = min(max((int)floorf(x), 0), W0 - 1);
    int y0 = min(max((int)floorf(y), 0), H0 - 1);
    int x1 = min(x0 + 1, W0 - 1);
    int y1 = min(y0 + 1, H0 - 1);
    // clip-first weight semantics (zero weight at exact upper edge)
    float wxh = x - (float)x0, wxl = (float)x1 - x;
    float wyh = y - (float)y0, wyl = (float)y1 - y;
    float wa = wxl * wyl, wb = wxl * wyh, wc = wxh * wyl, wd = wxh * wyh;
    const float4* base = (const float4*)(fmap1 + (size_t)b * H0 * W0 * NC);
    float4 Ia = base[(y0 * W0 + x0) * (NC / 4) + lane];
    float4 Ib = base[(y1 * W0 + x0) * (NC / 4) + lane];
    float4 Ic = base[(y0 * W0 + x1) * (NC / 4) + lane];
    float4 Id = base[(y1 * W0 + x1) * (NC / 4) + lane];
    float vx = wa * Ia.x + wb * Ib.x + wc * Ic.x + wd * Id.x;
    float vy = wa * Ia.y + wb * Ib.y + wc * Ic.y + wd * Id.y;
    float vz = wa * Ia.z + wb * Ib.z + wc * Ic.z + wd * Id.z;
    float vw = wa * Ia.w + wb * Ib.w + wc * Ic.w + wd * Id.w;
    float ss = wave_reduce_sum(vx * vx + vy * vy + vz * vz + vw * vw);
    float inv = 1.0f / (sqrtf(ss) + 1e-6f);
    float4 o; o.x = vx * inv; o.y = vy * inv; o.z = vz * inv; o.w = vw * inv;
    ((float4*)(feat1 + (size_t)pt * NC))[lane] = o;
}

// One wave per pixel: L2-normalize over C.
__global__ __launch_bounds__(256)
void norm_kernel(const float* __restrict__ in, float* __restrict__ out, int npix) {
    int p = blockIdx.x * 4 + (threadIdx.x >> 6);
    if (p >= npix) return;
    int lane = threadIdx.x & 63;
    float4 v = ((const float4*)in)[(size_t)p * (NC / 4) + lane];
    float ss = wave_reduce_sum(v.x * v.x + v.y * v.y + v.z * v.z + v.w * v.w);
    float inv = 1.0f / (sqrtf(ss) + 1e-6f);
    float4 o; o.x = v.x * inv; o.y = v.y * inv; o.z = v.z * inv; o.w = v.w * inv;
    ((float4*)out)[(size_t)p * (NC / 4) + lane] = o;
}

// jax.image.resize bilinear antialias 2x downsample: separable [1,3,3,1]/8,
// OOB taps dropped + renormalized at edges. One wave per OUTPUT pixel.
// Writes both raw (for cascade) and normalized output.
__global__ __launch_bounds__(256)
void down_kernel(const float* __restrict__ in, float* __restrict__ raw_out,
                 float* __restrict__ norm_out, int Hi, int Wi) {
    int Ho = Hi >> 1, Wo = Wi >> 1;
    int wid = blockIdx.x * 4 + (threadIdx.x >> 6);
    int total = NB * Ho * Wo;
    if (wid >= total) return;
    int lane = threadIdx.x & 63;
    int b = wid / (Ho * Wo);
    int rem = wid - b * Ho * Wo;
    int yo = rem / Wo, xo = rem - yo * Wo;
    float wy[4], wx[4]; int ty[4], tx[4];
    float sy = 0.f, sx = 0.f;
    for (int j = 0; j < 4; ++j) {
        float w = (j == 0 || j == 3) ? 1.f : 3.f;
        int yi = 2 * yo - 1 + j;
        float wyj = (yi >= 0 && yi < Hi) ? w : 0.f;
        ty[j] = min(max(yi, 0), Hi - 1); wy[j] = wyj; sy += wyj;
        int xi = 2 * xo - 1 + j;
        float wxj = (xi >= 0 && xi < Wi) ? w : 0.f;
        tx[j] = min(max(xi, 0), Wi - 1); wx[j] = wxj; sx += wxj;
    }
    float inv_s = 1.f / (sy * sx);
    float ax = 0.f, ay = 0.f, az = 0.f, aw = 0.f;
    const float4* basep = (const float4*)(in + (size_t)b * Hi * Wi * NC);
    for (int jy = 0; jy < 4; ++jy) {
        if (wy[jy] == 0.f) continue;
        for (int jx = 0; jx < 4; ++jx) {
            float w = wy[jy] * wx[jx];
            if (w == 0.f) continue;
            float4 v = basep[(ty[jy] * Wi + tx[jx]) * (NC / 4) + lane];
            ax += w * v.x; ay += w * v.y; az += w * v.z; aw += w * v.w;
        }
    }
    ax *= inv_s; ay *= inv_s; az *= inv_s; aw *= inv_s;
    float ss = wave_reduce_sum(ax * ax + ay * ay + az * az + aw * aw);
    float inv = 1.f / (sqrtf(ss) + 1e-6f);
    size_t po = ((size_t)b * Ho * Wo + (size_t)yo * Wo + xo) * (NC / 4) + lane;
    float4 r;  r.x = ax;        r.y = ay;        r.z = az;        r.w = aw;
    float4 nn; nn.x = ax * inv; nn.y = ay * inv; nn.z = az * inv; nn.w = aw * inv;
    ((float4*)raw_out)[po]  = r;
    ((float4*)norm_out)[po] = nn;
}

// One block per point. Wave w = level.
// Dot phase: lane = (pixel-quad pq = lane>>2, channel-quad cg = lane&3).
// 16 pixels in flight per iteration; lanes of a quad read 64 B CONTIGUOUS
// (channel float4 index j*4+cg) -> every global_load_dwordx4 is 16 fully
// utilized cache lines (coalescing optimum) instead of 64 divergent lines.
// feat1 fragments preloaded LDS->VGPR once (16 float4/lane, cg-dependent).
// Per-pixel reduce = 2 shfl_xor over the cg bits.
__global__ __launch_bounds__(256)
void corr_kernel(const float* __restrict__ feat1,
                 const float* __restrict__ coords2,
                 const float* __restrict__ f2n0, const float* __restrict__ f2n1,
                 const float* __restrict__ f2n2, const float* __restrict__ f2n3,
                 float* __restrict__ out) {
    __shared__ float f1s[NC];
    __shared__ float Ds[NLVL][64];
    int pt = blockIdx.x;
    int b  = pt / NPTS;
    int t  = threadIdx.x;
    f1s[t] = feat1[(size_t)pt * NC + t];
    __syncthreads();

    int w    = t >> 6;        // level
    int lane = t & 63;
    int Wl = W0 >> w, Hl = H0 >> w;
    float invs = 1.0f / (float)(1 << w);
    float cx = coords2[pt * 2 + 0] * invs;
    float cy = coords2[pt * 2 + 1] * invs;
    int ix = (int)floorf(cx), iy = (int)floorf(cy);

    const float* f2 = (w == 0) ? f2n0 : (w == 1) ? f2n1 : (w == 2) ? f2n2 : f2n3;

    int cg = lane & 3;        // channel-quad id (which interleaved float4 set)
    int pq = lane >> 2;       // pixel slot within iteration (0..15)

    // Preload this lane's feat1 fragment: float4 indices j*4+cg, j=0..15.
    const float4* f1v = (const float4*)f1s;
    float4 a[16];
#pragma unroll
    for (int j = 0; j < 16; ++j) a[j] = f1v[j * 4 + cg];

#pragma unroll
    for (int i = 0; i < 4; ++i) {
        int p  = i * 16 + pq;            // grid pixel 0..63
        int jx = p & 7, jy = p >> 3;
        int px = min(max(ix - 3 + jx, 0), Wl - 1);
        int py = min(max(iy - 3 + jy, 0), Hl - 1);
        const float4* pix = (const float4*)(f2 + (((size_t)b * Hl + py) * Wl + px) * NC);
        float acc = 0.f;
#pragma unroll
        for (int j = 0; j < 16; ++j) {
            float4 v = pix[j * 4 + cg];  // quad lanes cover 64 B contiguous
            acc += a[j].x * v.x + a[j].y * v.y + a[j].z * v.z + a[j].w * v.w;
        }
        acc += __shfl_xor(acc, 1, 64);
        acc += __shfl_xor(acc, 2, 64);
        if (cg == 0) Ds[w][p] = acc;
    }
    __syncthreads();

    if (lane < NK) {
        int tyk = lane / 7, txk = lane % 7;
        float dx = (float)(txk - 3), dy = (float)(tyk - 3);
        float x = fminf(fmaxf(cx + dx, 0.f), (float)(Wl - 1));
        float y = fminf(fmaxf(cy + dy, 0.f), (float)(Hl - 1));
        int x0 = (int)floorf(x);
        int y0 = (int)floorf(y);
        int x1 = min(x0 + 1, Wl - 1);
        int y1 = min(y0 + 1, Hl - 1);
        float wxh = x - (float)x0, wxl = (float)x1 - x;  // both 0 at exact upper edge
        float wyh = y - (float)y0, wyl = (float)y1 - y;
        int sx0 = min(max(x0 - ix + 3, 0), 7);
        int sx1 = min(max(x1 - ix + 3, 0), 7);
        int sy0 = min(max(y0 - iy + 3, 0), 7);
        int sy1 = min(max(y1 - iy + 3, 0), 7);
        float v = wxl * wyl * Ds[w][sy0 * 8 + sx0]
                + wxl * wyh * Ds[w][sy1 * 8 + sx0]
                + wxh * wyl * Ds[w][sy0 * 8 + sx1]
                + wxh * wyh * Ds[w][sy1 * 8 + sx1];
        out[(size_t)pt * (NLVL * NK) + w * NK + lane] = v;
    }
}

extern "C" void kernel_launch(void* const* d_in, const int* in_sizes, int n_in,
                              void* d_out, int out_size, void* d_ws, size_t ws_size,
                              hipStream_t stream) {
    const float* fmap1   = (const float*)d_in[0];
    const float* fmap2   = (const float*)d_in[1];
    const float* coords1 = (const float*)d_in[2];
    const float* coords2 = (const float*)d_in[3];
    float* out = (float*)d_out;
    float* ws  = (float*)d_ws;

    // workspace layout (floats)
    float* feat1 = ws;                       // 2*4096*256      = 2097152
    float* f2n0  = ws + 2097152;             // 2*64*64*256     = 2097152
    float* raw1  = ws + 4194304;             // 2*32*32*256     = 524288
    float* f2n1  = ws + 4718592;             // 524288
    float* raw2  = ws + 5242880;             // 2*16*16*256     = 131072
    float* f2n2  = ws + 5373952;             // 131072
    float* raw3  = ws + 5505024;             // 2*8*8*256       = 32768
    float* f2n3  = ws + 5537792;             // 32768
    // total = 5570560 floats = 21.25 MiB

    // feat1 = normalize(bilinear(fmap1, coords1))
    feat1_kernel<<<(NB * NPTS) / 4, 256, 0, stream>>>(fmap1, coords1, feat1);
    // level 0 normalize
    norm_kernel<<<(NB * H0 * W0 + 3) / 4, 256, 0, stream>>>(fmap2, f2n0, NB * H0 * W0);
    // cascaded pyramid with fused normalize
    down_kernel<<<(NB * 32 * 32 + 3) / 4, 256, 0, stream>>>(fmap2, raw1, f2n1, 64, 64);
    down_kernel<<<(NB * 16 * 16 + 3) / 4, 256, 0, stream>>>(raw1, raw2, f2n2, 32, 32);
    down_kernel<<<(NB * 8 * 8 + 3) / 4, 256, 0, stream>>>(raw2, raw3, f2n3, 16, 16);
    // correlation
    corr_kernel<<<NB * NPTS, 256, 0, stream>>>(feat1, coords2, f2n0, f2n1, f2n2, f2n3, out);
}

// Round 3
// 171.159 us; speedup vs baseline: 1.7981x; 1.3336x over previous
//
#include <hip/hip_runtime.h>
#include <math.h>

#define NB   2
#define H0   64
#define W0   64
#define NC   256
#define NPTS 4096
#define NLVL 4
#define NK   49   // (2*3+1)^2

__device__ __forceinline__ float wave_reduce_sum(float v) {
    for (int m = 32; m >= 1; m >>= 1)
        v += __shfl_xor(v, m, 64);
    return v;
}

// float -> bf16 round-to-nearest-even (no NaN handling needed here)
__device__ __forceinline__ unsigned short f2bf(float f) {
    unsigned int u = __float_as_uint(f);
    u += 0x7fffu + ((u >> 16) & 1u);
    return (unsigned short)(u >> 16);
}

// jax.image.resize bilinear antialias 2x downsample: separable [1,3,3,1]/8,
// OOB taps dropped + renormalized at edges. One wave per OUTPUT pixel.
// Writes raw fp32 (optional, for cascade) and bf16 normalized output.
__device__ __forceinline__ void down_norm(const float* __restrict__ in,
                                          float* __restrict__ raw_out,
                                          unsigned short* __restrict__ norm_out,
                                          int Hi, int Wi, int wid, int lane) {
    int Ho = Hi >> 1, Wo = Wi >> 1;
    int b = wid / (Ho * Wo);
    int rem = wid - b * (Ho * Wo);
    int yo = rem / Wo, xo = rem - yo * Wo;
    float wy[4], wx[4]; int ty[4], tx[4];
    float sy = 0.f, sx = 0.f;
    for (int j = 0; j < 4; ++j) {
        float w = (j == 0 || j == 3) ? 1.f : 3.f;
        int yi = 2 * yo - 1 + j;
        float wyj = (yi >= 0 && yi < Hi) ? w : 0.f;
        ty[j] = min(max(yi, 0), Hi - 1); wy[j] = wyj; sy += wyj;
        int xi = 2 * xo - 1 + j;
        float wxj = (xi >= 0 && xi < Wi) ? w : 0.f;
        tx[j] = min(max(xi, 0), Wi - 1); wx[j] = wxj; sx += wxj;
    }
    float inv_s = 1.f / (sy * sx);
    float ax = 0.f, ay = 0.f, az = 0.f, aw = 0.f;
    const float4* basep = (const float4*)(in + (size_t)b * Hi * Wi * NC);
    for (int jy = 0; jy < 4; ++jy) {
        if (wy[jy] == 0.f) continue;
        for (int jx = 0; jx < 4; ++jx) {
            float w = wy[jy] * wx[jx];
            if (w == 0.f) continue;
            float4 v = basep[(ty[jy] * Wi + tx[jx]) * (NC / 4) + lane];
            ax += w * v.x; ay += w * v.y; az += w * v.z; aw += w * v.w;
        }
    }
    ax *= inv_s; ay *= inv_s; az *= inv_s; aw *= inv_s;
    float ss = wave_reduce_sum(ax * ax + ay * ay + az * az + aw * aw);
    float inv = 1.f / (sqrtf(ss) + 1e-6f);
    size_t po = ((size_t)b * Ho * Wo + (size_t)yo * Wo + xo) * (NC / 4) + lane;
    if (raw_out) {
        float4 r; r.x = ax; r.y = ay; r.z = az; r.w = aw;
        ((float4*)raw_out)[po] = r;
    }
    ushort4 nn;
    nn.x = f2bf(ax * inv); nn.y = f2bf(ay * inv);
    nn.z = f2bf(az * inv); nn.w = f2bf(aw * inv);
    ((ushort4*)norm_out)[po] = nn;
}

// Level 3 directly from raw1 (level-1 raw, 32x32): two downsample stages
// composed into one 10-tap-per-dim filter, with each stage's edge
// renormalization composed exactly.
__device__ __forceinline__ void down3_composed(const float* __restrict__ raw1,
                                               unsigned short* __restrict__ norm_out,
                                               int wid, int lane) {
    int b = wid / 64;
    int rem = wid - b * 64;
    int yo = rem >> 3, xo = rem & 7;             // level-3 coords (8x8)
    float Wt[2][10]; int base[2];
    for (int d = 0; d < 2; ++d) {
        int o = d ? xo : yo;
        base[d] = 4 * o - 3;
        float W[10];
        for (int k = 0; k < 10; ++k) W[k] = 0.f;
        float S2 = 0.f;
        for (int j = 0; j < 4; ++j) {            // level-2 intermediate taps (size 16)
            int yj = 2 * o - 1 + j;
            if (yj < 0 || yj >= 16) continue;
            float wj = (j == 0 || j == 3) ? 1.f : 3.f;
            S2 += wj;
            int yi0 = 2 * yj - 1;
            float wi[4], s1 = 0.f;
            for (int i2 = 0; i2 < 4; ++i2) {     // raw1 taps (size 32)
                int yi = yi0 + i2;
                wi[i2] = (yi >= 0 && yi < 32) ? ((i2 == 0 || i2 == 3) ? 1.f : 3.f) : 0.f;
                s1 += wi[i2];
            }
            float sc = wj / s1;
            for (int i2 = 0; i2 < 4; ++i2)
                if (wi[i2] > 0.f) W[yi0 + i2 - base[d]] += wi[i2] * sc;
        }
        float invS = 1.f / S2;
        for (int k = 0; k < 10; ++k) Wt[d][k] = W[k] * invS;
    }
    float ax = 0.f, ay = 0.f, az = 0.f, aw = 0.f;
    const float4* basep = (const float4*)(raw1 + (size_t)b * 32 * 32 * NC);
    for (int ky = 0; ky < 10; ++ky) {
        float wy = Wt[0][ky];
        if (wy == 0.f) continue;
        int yi = base[0] + ky;
        for (int kx = 0; kx < 10; ++kx) {
            float wx = Wt[1][kx];
            if (wx == 0.f) continue;
            int xi = base[1] + kx;
            float4 v = basep[(yi * 32 + xi) * (NC / 4) + lane];
            float wgt = wy * wx;
            ax += wgt * v.x; ay += wgt * v.y; az += wgt * v.z; aw += wgt * v.w;
        }
    }
    float ss = wave_reduce_sum(ax * ax + ay * ay + az * az + aw * aw);
    float inv = 1.f / (sqrtf(ss) + 1e-6f);
    size_t po = ((size_t)b * 64 + yo * 8 + xo) * (NC / 4) + lane;
    ushort4 nn;
    nn.x = f2bf(ax * inv); nn.y = f2bf(ay * inv);
    nn.z = f2bf(az * inv); nn.w = f2bf(aw * inv);
    ((ushort4*)norm_out)[po] = nn;
}

// Fused preprocessing: blocks [0,2048) feat1, [2048,4096) norm level0,
// [4096,4608) downsample level1. All three independent.
__global__ __launch_bounds__(256)
void pre_kernel(const float* __restrict__ fmap1,
                const float* __restrict__ fmap2,
                const float* __restrict__ coords1,
                float* __restrict__ feat1,
                unsigned short* __restrict__ f2n0,
                float* __restrict__ raw1,
                unsigned short* __restrict__ f2n1) {
    int blk  = blockIdx.x;
    int wv   = threadIdx.x >> 6;
    int lane = threadIdx.x & 63;
    if (blk < 2048) {
        // feat1 = normalize(bilinear(fmap1, coords1)); one wave per point
        int pt = blk * 4 + wv;
        int b = pt / NPTS;
        float x = coords1[pt * 2 + 0];
        float y = coords1[pt * 2 + 1];
        int x0 = min(max((int)floorf(x), 0), W0 - 1);
        int y0 = min(max((int)floorf(y), 0), H0 - 1);
        int x1 = min(x0 + 1, W0 - 1);
        int y1 = min(y0 + 1, H0 - 1);
        float wxh = x - (float)x0, wxl = (float)x1 - x;   // clip-first semantics
        float wyh = y - (float)y0, wyl = (float)y1 - y;
        float wa = wxl * wyl, wb = wxl * wyh, wc = wxh * wyl, wd = wxh * wyh;
        const float4* base = (const float4*)(fmap1 + (size_t)b * H0 * W0 * NC);
        float4 Ia = base[(y0 * W0 + x0) * (NC / 4) + lane];
        float4 Ib = base[(y1 * W0 + x0) * (NC / 4) + lane];
        float4 Ic = base[(y0 * W0 + x1) * (NC / 4) + lane];
        float4 Id = base[(y1 * W0 + x1) * (NC / 4) + lane];
        float vx = wa * Ia.x + wb * Ib.x + wc * Ic.x + wd * Id.x;
        float vy = wa * Ia.y + wb * Ib.y + wc * Ic.y + wd * Id.y;
        float vz = wa * Ia.z + wb * Ib.z + wc * Ic.z + wd * Id.z;
        float vw = wa * Ia.w + wb * Ib.w + wc * Ic.w + wd * Id.w;
        float ss = wave_reduce_sum(vx * vx + vy * vy + vz * vz + vw * vw);
        float inv = 1.0f / (sqrtf(ss) + 1e-6f);
        float4 o; o.x = vx * inv; o.y = vy * inv; o.z = vz * inv; o.w = vw * inv;
        ((float4*)(feat1 + (size_t)pt * NC))[lane] = o;
    } else if (blk < 4096) {
        // level-0 normalize -> bf16
        int p = (blk - 2048) * 4 + wv;
        float4 v = ((const float4*)fmap2)[(size_t)p * (NC / 4) + lane];
        float ss = wave_reduce_sum(v.x * v.x + v.y * v.y + v.z * v.z + v.w * v.w);
        float inv = 1.0f / (sqrtf(ss) + 1e-6f);
        ushort4 nn;
        nn.x = f2bf(v.x * inv); nn.y = f2bf(v.y * inv);
        nn.z = f2bf(v.z * inv); nn.w = f2bf(v.w * inv);
        ((ushort4*)f2n0)[(size_t)p * (NC / 4) + lane] = nn;
    } else {
        // level-1 downsample (64x64 -> 32x32), raw fp32 + bf16 norm
        int wid = (blk - 4096) * 4 + wv;
        down_norm(fmap2, raw1, f2n1, H0, W0, wid, lane);
    }
}

// Fused small levels: blocks [0,128) level2 from raw1; [128,160) level3
// (composed two-stage filter from raw1 — no raw2 dependency).
__global__ __launch_bounds__(256)
void small_kernel(const float* __restrict__ raw1,
                  unsigned short* __restrict__ f2n2,
                  unsigned short* __restrict__ f2n3) {
    int blk  = blockIdx.x;
    int wv   = threadIdx.x >> 6;
    int lane = threadIdx.x & 63;
    if (blk < 128) {
        int wid = blk * 4 + wv;
        down_norm(raw1, (float*)nullptr, f2n2, 32, 32, wid, lane);
    } else {
        int wid = (blk - 128) * 4 + wv;
        down3_composed(raw1, f2n3, wid, lane);
    }
}

// One block per point. Wave w = level.
// Dot phase: lane = (pixel slot pq = lane>>2, channel group cg = lane&3).
// bf16 pyramid: pixel = 512 B = 32 x 16B chunks; lane reads chunks j*4+cg
// (j=0..7) so each quad covers one contiguous 64 B line -> every
// global_load_dwordx4 is 16 fully-utilized lines; 32 loads/wave (half of fp32).
// feat1 stays fp32 (register fragments from LDS); bf16 decode via shift/and
// bit tricks (no cvt instructions). Per-pixel reduce = 2 shfl_xor over cg.
__global__ __launch_bounds__(256)
void corr_kernel(const float* __restrict__ feat1,
                 const float* __restrict__ coords2,
                 const unsigned short* __restrict__ f2n0,
                 const unsigned short* __restrict__ f2n1,
                 const unsigned short* __restrict__ f2n2,
                 const unsigned short* __restrict__ f2n3,
                 float* __restrict__ out) {
    __shared__ float f1s[NC];
    __shared__ float Ds[NLVL][64];
    int pt = blockIdx.x;
    int b  = pt / NPTS;
    int t  = threadIdx.x;
    f1s[t] = feat1[(size_t)pt * NC + t];
    __syncthreads();

    int w    = t >> 6;        // level
    int lane = t & 63;
    int Wl = W0 >> w, Hl = H0 >> w;
    float invs = 1.0f / (float)(1 << w);
    float cx = coords2[pt * 2 + 0] * invs;
    float cy = coords2[pt * 2 + 1] * invs;
    int ix = (int)floorf(cx), iy = (int)floorf(cy);

    const unsigned short* f2 = (w == 0) ? f2n0 : (w == 1) ? f2n1 : (w == 2) ? f2n2 : f2n3;

    int cg = lane & 3;        // channel chunk group
    int pq = lane >> 2;       // pixel slot (0..15)

    // feat1 fragments: chunk m = j*4+cg covers channels m*8..m*8+7 -> float4
    // indices 2m, 2m+1.
    const float4* f1v = (const float4*)f1s;
    float4 a[16];
#pragma unroll
    for (int j = 0; j < 8; ++j) {
        int m = j * 4 + cg;
        a[2 * j]     = f1v[2 * m];
        a[2 * j + 1] = f1v[2 * m + 1];
    }

#pragma unroll
    for (int i = 0; i < 4; ++i) {
        int p  = i * 16 + pq;            // grid pixel 0..63
        int jx = p & 7, jy = p >> 3;
        int px = min(max(ix - 3 + jx, 0), Wl - 1);
        int py = min(max(iy - 3 + jy, 0), Hl - 1);
        const uint4* pix = (const uint4*)(f2 + (((size_t)b * Hl + py) * Wl + px) * NC);
        float acc = 0.f;
#pragma unroll
        for (int j = 0; j < 8; ++j) {
            uint4 u = pix[j * 4 + cg];   // quad lanes cover 64 B contiguous
            float4 a0 = a[2 * j], a1 = a[2 * j + 1];
            acc += a0.x * __uint_as_float(u.x << 16)
                 + a0.y * __uint_as_float(u.x & 0xffff0000u)
                 + a0.z * __uint_as_float(u.y << 16)
                 + a0.w * __uint_as_float(u.y & 0xffff0000u)
                 + a1.x * __uint_as_float(u.z << 16)
                 + a1.y * __uint_as_float(u.z & 0xffff0000u)
                 + a1.z * __uint_as_float(u.w << 16)
                 + a1.w * __uint_as_float(u.w & 0xffff0000u);
        }
        acc += __shfl_xor(acc, 1, 64);
        acc += __shfl_xor(acc, 2, 64);
        if (cg == 0) Ds[w][p] = acc;
    }
    __syncthreads();

    if (lane < NK) {
        int tyk = lane / 7, txk = lane % 7;
        float dx = (float)(txk - 3), dy = (float)(tyk - 3);
        float x = fminf(fmaxf(cx + dx, 0.f), (float)(Wl - 1));
        float y = fminf(fmaxf(cy + dy, 0.f), (float)(Hl - 1));
        int x0 = (int)floorf(x);
        int y0 = (int)floorf(y);
        int x1 = min(x0 + 1, Wl - 1);
        int y1 = min(y0 + 1, Hl - 1);
        float wxh = x - (float)x0, wxl = (float)x1 - x;  // both 0 at exact upper edge
        float wyh = y - (float)y0, wyl = (float)y1 - y;
        int sx0 = min(max(x0 - ix + 3, 0), 7);
        int sx1 = min(max(x1 - ix + 3, 0), 7);
        int sy0 = min(max(y0 - iy + 3, 0), 7);
        int sy1 = min(max(y1 - iy + 3, 0), 7);
        float v = wxl * wyl * Ds[w][sy0 * 8 + sx0]
                + wxl * wyh * Ds[w][sy1 * 8 + sx0]
                + wxh * wyl * Ds[w][sy0 * 8 + sx1]
                + wxh * wyh * Ds[w][sy1 * 8 + sx1];
        out[(size_t)pt * (NLVL * NK) + w * NK + lane] = v;
    }
}

extern "C" void kernel_launch(void* const* d_in, const int* in_sizes, int n_in,
                              void* d_out, int out_size, void* d_ws, size_t ws_size,
                              hipStream_t stream) {
    const float* fmap1   = (const float*)d_in[0];
    const float* fmap2   = (const float*)d_in[1];
    const float* coords1 = (const float*)d_in[2];
    const float* coords2 = (const float*)d_in[3];
    float* out = (float*)d_out;
    float* ws  = (float*)d_ws;

    // workspace layout (float offsets; bf16 arrays cast from float storage)
    float*          feat1 = ws;                           // 2,097,152 floats
    float*          raw1  = ws + 2097152;                 //   524,288 floats
    unsigned short* f2n0  = (unsigned short*)(ws + 2621440); // 2,097,152 bf16
    unsigned short* f2n1  = (unsigned short*)(ws + 3670016); //   524,288 bf16
    unsigned short* f2n2  = (unsigned short*)(ws + 3932160); //   131,072 bf16
    unsigned short* f2n3  = (unsigned short*)(ws + 3997696); //    32,768 bf16
    // total 4,014,080 floats = 15.3 MiB

    pre_kernel<<<4608, 256, 0, stream>>>(fmap1, fmap2, coords1, feat1, f2n0, raw1, f2n1);
    small_kernel<<<160, 256, 0, stream>>>(raw1, f2n2, f2n3);
    corr_kernel<<<NB * NPTS, 256, 0, stream>>>(feat1, coords2, f2n0, f2n1, f2n2, f2n3, out);
}